// Round 1
// baseline (3817.088 us; speedup 1.0000x reference)
//
#include <hip/hip_runtime.h>

#define NN 50000
#define NE 600000
#define NG 1000
#define IND 16
#define HID 128
#define DESCD 17
#define NL 3
#define BN_EPS 1e-5f

// ---------------- h = x @ Wp + bp ----------------
__global__ __launch_bounds__(256) void k_proj(const float* __restrict__ x,
                                              const float* __restrict__ Wp,
                                              const float* __restrict__ bp,
                                              float* __restrict__ h) {
    int idx = blockIdx.x * blockDim.x + threadIdx.x;
    if (idx >= NN * HID) return;
    int row = idx >> 7, col = idx & 127;
    const float* xr = x + (size_t)row * IND;
    float acc = bp[col];
#pragma unroll
    for (int k = 0; k < IND; k++) acc += xr[k] * Wp[k * HID + col];
    h[idx] = acc;
}

// ---------------- edge gather + relu + scatter-add ----------------
// thread per (edge, 4 feats): NE*32 threads
__global__ __launch_bounds__(256) void k_edge(const float* __restrict__ h,
                                              const float* __restrict__ ea,
                                              const int* __restrict__ src,
                                              const int* __restrict__ dst,
                                              float* __restrict__ aggr) {
    int idx = blockIdx.x * blockDim.x + threadIdx.x;
    if (idx >= NE * 32) return;
    int e = idx >> 5;
    int f4 = (idx & 31) << 2;
    int s = src[e], d = dst[e];
    float4 v = *(const float4*)&ea[(size_t)e * HID + f4];
    float4 hv = *(const float4*)&h[(size_t)s * HID + f4];
    float m0 = fmaxf(v.x + hv.x, 0.f);
    float m1 = fmaxf(v.y + hv.y, 0.f);
    float m2 = fmaxf(v.z + hv.z, 0.f);
    float m3 = fmaxf(v.w + hv.w, 0.f);
    float* ap = &aggr[(size_t)d * HID + f4];
    atomicAdd(ap + 0, m0);
    atomicAdd(ap + 1, m1);
    atomicAdd(ap + 2, m2);
    atomicAdd(ap + 3, m3);
}

// ---------------- tiled GEMM: out = (A1 [+A2]) @ B + bias, optional relu ----
// A: [N,128], B: [128,128] row-major, out: [N,128]. Block = 256 thr, 64-row tile.
template <bool ADD2, bool RELU>
__global__ __launch_bounds__(256) void k_gemm(const float* __restrict__ A1,
                                              const float* __restrict__ A2,
                                              const float* __restrict__ B,
                                              const float* __restrict__ bias,
                                              float* __restrict__ out, int N) {
    __shared__ float sB[HID * HID];   // 64 KB
    __shared__ float sA[64 * 136];    // 34.8 KB, padded stride vs bank conflicts
    const int t = threadIdx.x;
    for (int i = t * 4; i < HID * HID; i += 1024)
        *(float4*)&sB[i] = *(const float4*)&B[i];

    const int colg = t & 15;   // 16 col groups x 8 cols
    const int rowg = t >> 4;   // 16 row groups x 4 rows
    const int c0 = colg * 8;

    float bs[8];
#pragma unroll
    for (int j = 0; j < 8; j++) bs[j] = bias[c0 + j];

    for (int rowBase = blockIdx.x * 64; rowBase < N; rowBase += gridDim.x * 64) {
        __syncthreads();
        int rcnt = min(64, N - rowBase);
        for (int i = t * 4; i < rcnt * HID; i += 1024) {
            int r = i >> 7, c = i & 127;
            float4 v = *(const float4*)&A1[(size_t)(rowBase + r) * HID + c];
            if (ADD2) {
                float4 w = *(const float4*)&A2[(size_t)(rowBase + r) * HID + c];
                v.x += w.x; v.y += w.y; v.z += w.z; v.w += w.w;
            }
            *(float4*)&sA[r * 136 + c] = v;
        }
        __syncthreads();

        float acc[4][8];
#pragma unroll
        for (int r = 0; r < 4; r++)
#pragma unroll
            for (int c = 0; c < 8; c++) acc[r][c] = 0.f;

        for (int k = 0; k < HID; k++) {
            float4 b0 = *(float4*)&sB[k * HID + c0];
            float4 b1 = *(float4*)&sB[k * HID + c0 + 4];
            float a[4];
#pragma unroll
            for (int r = 0; r < 4; r++) a[r] = sA[(rowg * 4 + r) * 136 + k];
#pragma unroll
            for (int r = 0; r < 4; r++) {
                acc[r][0] += a[r] * b0.x;
                acc[r][1] += a[r] * b0.y;
                acc[r][2] += a[r] * b0.z;
                acc[r][3] += a[r] * b0.w;
                acc[r][4] += a[r] * b1.x;
                acc[r][5] += a[r] * b1.y;
                acc[r][6] += a[r] * b1.z;
                acc[r][7] += a[r] * b1.w;
            }
        }

#pragma unroll
        for (int r = 0; r < 4; r++) {
            int row = rowBase + rowg * 4 + r;
            if (row < N) {
                float4 o0, o1;
                o0.x = acc[r][0] + bs[0]; o0.y = acc[r][1] + bs[1];
                o0.z = acc[r][2] + bs[2]; o0.w = acc[r][3] + bs[3];
                o1.x = acc[r][4] + bs[4]; o1.y = acc[r][5] + bs[5];
                o1.z = acc[r][6] + bs[6]; o1.w = acc[r][7] + bs[7];
                if (RELU) {
                    o0.x = fmaxf(o0.x, 0.f); o0.y = fmaxf(o0.y, 0.f);
                    o0.z = fmaxf(o0.z, 0.f); o0.w = fmaxf(o0.w, 0.f);
                    o1.x = fmaxf(o1.x, 0.f); o1.y = fmaxf(o1.y, 0.f);
                    o1.z = fmaxf(o1.z, 0.f); o1.w = fmaxf(o1.w, 0.f);
                }
                *(float4*)&out[(size_t)row * HID + c0] = o0;
                *(float4*)&out[(size_t)row * HID + c0 + 4] = o1;
            }
        }
    }
}

// ---------------- BN stats: per-column sum and sumsq ----------------
__global__ __launch_bounds__(256) void k_bnstats(const float* __restrict__ z,
                                                 float* __restrict__ stats) {
    __shared__ float sh[512];
    int t = threadIdx.x;
    int col = t & 127, half = t >> 7;
    int r0 = blockIdx.x * 512 + half;
    int rend = min(NN, blockIdx.x * 512 + 512);
    float s = 0.f, q = 0.f;
    for (int r = r0; r < rend; r += 2) {
        float v = z[(size_t)r * HID + col];
        s += v; q += v * v;
    }
    sh[t] = s;
    sh[256 + t] = q;
    __syncthreads();
    if (t < 128) {
        atomicAdd(&stats[t], sh[t] + sh[t + 128]);
        atomicAdd(&stats[128 + t], sh[256 + t] + sh[256 + t + 128]);
    }
}

// stats -> scale/shift in place
__global__ void k_bnfin(float* __restrict__ stats, const float* __restrict__ gamma,
                        const float* __restrict__ beta) {
    int c = threadIdx.x;
    float mean = stats[c] * (1.f / NN);
    float var = stats[128 + c] * (1.f / NN) - mean * mean;
    float sc = rsqrtf(var + BN_EPS) * gamma[c];
    stats[c] = sc;
    stats[128 + c] = beta[c] - mean * sc;
}

// h = relu(z*scale + shift)
__global__ __launch_bounds__(256) void k_bnapply(const float* __restrict__ z,
                                                 const float* __restrict__ stats,
                                                 float* __restrict__ h) {
    int idx = blockIdx.x * blockDim.x + threadIdx.x;
    if (idx >= NN * 32) return;
    int f4 = (idx & 31) << 2;
    size_t base = (size_t)(idx >> 5) * HID + f4;
    float4 v = *(const float4*)&z[base];
    float4 sc = *(const float4*)&stats[f4];
    float4 sf = *(const float4*)&stats[128 + f4];
    float4 o;
    o.x = fmaxf(v.x * sc.x + sf.x, 0.f);
    o.y = fmaxf(v.y * sc.y + sf.y, 0.f);
    o.z = fmaxf(v.z * sc.z + sf.z, 0.f);
    o.w = fmaxf(v.w * sc.w + sf.w, 0.f);
    *(float4*)&h[base] = o;
}

// ---------------- pooling: segment sums + counts ----------------
__global__ __launch_bounds__(256) void k_pool(const float* __restrict__ h,
                                              const int* __restrict__ batch,
                                              float* __restrict__ psums,
                                              float* __restrict__ pcnt) {
    int idx = blockIdx.x * blockDim.x + threadIdx.x;
    if (idx >= NN * 32) return;
    int n = idx >> 5;
    int f4 = (idx & 31) << 2;
    int g = batch[n];
    float4 v = *(const float4*)&h[(size_t)n * HID + f4];
    float* pp = &psums[(size_t)g * HID + f4];
    atomicAdd(pp + 0, v.x);
    atomicAdd(pp + 1, v.y);
    atomicAdd(pp + 2, v.z);
    atomicAdd(pp + 3, v.w);
    if (f4 == 0) atomicAdd(&pcnt[g], 1.f);
}

// ---------------- final: out[g] = concat(pooled, desc) @ Wf + bf -----------
__global__ __launch_bounds__(256) void k_final(const float* __restrict__ psums,
                                               const float* __restrict__ pcnt,
                                               const float* __restrict__ mol,
                                               const float* __restrict__ Wf,
                                               const float* __restrict__ bf,
                                               float* __restrict__ out) {
    int gid = (blockIdx.x * blockDim.x + threadIdx.x) >> 6;
    int lane = threadIdx.x & 63;
    if (gid >= NG) return;
    float inv = 1.f / fmaxf(pcnt[gid], 1.f);
    float acc = psums[(size_t)gid * HID + lane] * inv * Wf[lane] +
                psums[(size_t)gid * HID + 64 + lane] * inv * Wf[64 + lane];
    if (lane < DESCD) acc += mol[(size_t)gid * DESCD + lane] * Wf[HID + lane];
#pragma unroll
    for (int o = 32; o > 0; o >>= 1) acc += __shfl_down(acc, o);
    if (lane == 0) out[gid] = acc + bf[0];
}

extern "C" void kernel_launch(void* const* d_in, const int* in_sizes, int n_in,
                              void* d_out, int out_size, void* d_ws, size_t ws_size,
                              hipStream_t stream) {
    const float* x     = (const float*)d_in[0];
    const int*   ei    = (const int*)d_in[1];
    const float* ea    = (const float*)d_in[2];
    const int*   batch = (const int*)d_in[3];
    const float* mol   = (const float*)d_in[4];
    const float* Wp    = (const float*)d_in[5];
    const float* bp    = (const float*)d_in[6];
    const float* W1    = (const float*)d_in[7];
    const float* b1    = (const float*)d_in[8];
    const float* W2    = (const float*)d_in[9];
    const float* b2    = (const float*)d_in[10];
    const float* gamma = (const float*)d_in[11];
    const float* beta  = (const float*)d_in[12];
    const float* Wf    = (const float*)d_in[13];
    const float* bf    = (const float*)d_in[14];
    float* out = (float*)d_out;

    float* ws    = (float*)d_ws;
    float* h     = ws;
    float* bufA  = h + (size_t)NN * HID;
    float* bufB  = bufA + (size_t)NN * HID;
    float* stats = bufB + (size_t)NN * HID;
    float* psums = stats + 256;
    float* pcnt  = psums + (size_t)NG * HID;

    const int* src = ei;
    const int* dst = ei + NE;

    k_proj<<<(NN * HID) / 256, 256, 0, stream>>>(x, Wp, bp, h);

    for (int l = 0; l < NL; l++) {
        hipMemsetAsync(bufA, 0, (size_t)NN * HID * sizeof(float), stream);
        k_edge<<<(NE * 32) / 256, 256, 0, stream>>>(h, ea, src, dst, bufA);
        k_gemm<true, true><<<(NN + 63) / 64, 256, 0, stream>>>(
            h, bufA, W1 + (size_t)l * HID * HID, b1 + l * HID, bufB, NN);
        k_gemm<false, false><<<(NN + 63) / 64, 256, 0, stream>>>(
            bufB, nullptr, W2 + (size_t)l * HID * HID, b2 + l * HID, bufA, NN);
        hipMemsetAsync(stats, 0, 256 * sizeof(float), stream);
        k_bnstats<<<(NN + 511) / 512, 256, 0, stream>>>(bufA, stats);
        k_bnfin<<<1, 128, 0, stream>>>(stats, gamma + l * HID, beta + l * HID);
        k_bnapply<<<(NN * 32) / 256, 256, 0, stream>>>(bufA, stats, h);
    }

    hipMemsetAsync(psums, 0, (size_t)(NG * HID + NG) * sizeof(float), stream);
    k_pool<<<(NN * 32) / 256, 256, 0, stream>>>(h, batch, psums, pcnt);
    k_final<<<(NG * 64 + 255) / 256, 256, 0, stream>>>(psums, pcnt, mol, Wf, bf, out);
}

// Round 2
// 1211.297 us; speedup vs baseline: 3.1512x; 3.1512x over previous
//
#include <hip/hip_runtime.h>

#define NN 50000
#define NE 600000
#define NG 1000
#define IND 16
#define HID 128
#define DESCD 17
#define NL 3
#define BN_EPS 1e-5f

// ---------------- CSR build: histogram of dst ----------------
__global__ __launch_bounds__(256) void k_hist(const int* __restrict__ dst,
                                              int* __restrict__ deg) {
    int e = blockIdx.x * blockDim.x + threadIdx.x;
    if (e >= NE) return;
    atomicAdd(&deg[dst[e]], 1);
}

// single-block exclusive scan over deg[0..NN) -> rowptr, cursor
__global__ __launch_bounds__(1024) void k_scan(const int* __restrict__ deg,
                                               int* __restrict__ rowptr,
                                               int* __restrict__ cursor) {
    __shared__ int ssum[1024];
    const int t = threadIdx.x;
    const int CH = (NN + 1023) / 1024;
    int beg = t * CH, end = min(beg + CH, NN);
    int s = 0;
    for (int i = beg; i < end; i++) s += deg[i];
    ssum[t] = s;
    __syncthreads();
    int val = s;
    for (int off = 1; off < 1024; off <<= 1) {
        int tmp = (t >= off) ? ssum[t - off] : 0;
        __syncthreads();
        if (t >= off) ssum[t] += tmp;
        __syncthreads();
    }
    int run = ssum[t] - val;  // exclusive prefix of this chunk
    for (int i = beg; i < end; i++) {
        rowptr[i] = run;
        cursor[i] = run;
        run += deg[i];
    }
    if (t == 1023) rowptr[NN] = run;
}

// scatter edge ids (and their src) into CSR order
__global__ __launch_bounds__(256) void k_fill(const int* __restrict__ src,
                                              const int* __restrict__ dst,
                                              int* __restrict__ cursor,
                                              int* __restrict__ eperm,
                                              int* __restrict__ sperm) {
    int e = blockIdx.x * blockDim.x + threadIdx.x;
    if (e >= NE) return;
    int pos = atomicAdd(&cursor[dst[e]], 1);
    eperm[pos] = e;
    sperm[pos] = src[e];
}

// ---------------- h = x @ Wp + bp ----------------
__global__ __launch_bounds__(256) void k_proj(const float* __restrict__ x,
                                              const float* __restrict__ Wp,
                                              const float* __restrict__ bp,
                                              float* __restrict__ h) {
    int idx = blockIdx.x * blockDim.x + threadIdx.x;
    if (idx >= NN * HID) return;
    int row = idx >> 7, col = idx & 127;
    const float* xr = x + (size_t)row * IND;
    float acc = bp[col];
#pragma unroll
    for (int k = 0; k < IND; k++) acc += xr[k] * Wp[k * HID + col];
    h[idx] = acc;
}

// ---------------- gather aggregation: z[n] = h[n] + sum_e relu(h[src]+ea[e])
// one wave (64 lanes) per node; each lane owns 2 features (float2)
__global__ __launch_bounds__(256) void k_aggr(const float* __restrict__ h,
                                              const float* __restrict__ ea,
                                              const int* __restrict__ eperm,
                                              const int* __restrict__ sperm,
                                              const int* __restrict__ rowptr,
                                              float* __restrict__ z) {
    int n = (blockIdx.x * blockDim.x + threadIdx.x) >> 6;
    int lane = threadIdx.x & 63;
    if (n >= NN) return;
    const int f = lane * 2;
    int beg = rowptr[n], end = rowptr[n + 1];
    float ax = 0.f, ay = 0.f;
    int i = beg;
    for (; i + 1 < end; i += 2) {
        int e0 = eperm[i], e1 = eperm[i + 1];
        int s0 = sperm[i], s1 = sperm[i + 1];
        float2 a0 = *(const float2*)&ea[(size_t)e0 * HID + f];
        float2 h0 = *(const float2*)&h[(size_t)s0 * HID + f];
        float2 a1 = *(const float2*)&ea[(size_t)e1 * HID + f];
        float2 h1 = *(const float2*)&h[(size_t)s1 * HID + f];
        ax += fmaxf(a0.x + h0.x, 0.f);
        ay += fmaxf(a0.y + h0.y, 0.f);
        ax += fmaxf(a1.x + h1.x, 0.f);
        ay += fmaxf(a1.y + h1.y, 0.f);
    }
    if (i < end) {
        int e0 = eperm[i], s0 = sperm[i];
        float2 a0 = *(const float2*)&ea[(size_t)e0 * HID + f];
        float2 h0 = *(const float2*)&h[(size_t)s0 * HID + f];
        ax += fmaxf(a0.x + h0.x, 0.f);
        ay += fmaxf(a0.y + h0.y, 0.f);
    }
    float2 hn = *(const float2*)&h[(size_t)n * HID + f];
    float2 o;
    o.x = ax + hn.x;
    o.y = ay + hn.y;
    *(float2*)&z[(size_t)n * HID + f] = o;
}

// ---------------- tiled GEMM: out = A @ B + bias, optional relu ----
// A: [N,128], B: [128,128] row-major, out: [N,128]. Block = 256 thr, 64-row tile.
template <bool RELU>
__global__ __launch_bounds__(256) void k_gemm(const float* __restrict__ A1,
                                              const float* __restrict__ B,
                                              const float* __restrict__ bias,
                                              float* __restrict__ out, int N) {
    __shared__ float sB[HID * HID];   // 64 KB
    __shared__ float sA[64 * 136];    // 34.8 KB, padded stride vs bank conflicts
    const int t = threadIdx.x;
    for (int i = t * 4; i < HID * HID; i += 1024)
        *(float4*)&sB[i] = *(const float4*)&B[i];

    const int colg = t & 15;   // 16 col groups x 8 cols
    const int rowg = t >> 4;   // 16 row groups x 4 rows
    const int c0 = colg * 8;

    float bs[8];
#pragma unroll
    for (int j = 0; j < 8; j++) bs[j] = bias[c0 + j];

    for (int rowBase = blockIdx.x * 64; rowBase < N; rowBase += gridDim.x * 64) {
        __syncthreads();
        int rcnt = min(64, N - rowBase);
        for (int i = t * 4; i < rcnt * HID; i += 1024) {
            int r = i >> 7, c = i & 127;
            float4 v = *(const float4*)&A1[(size_t)(rowBase + r) * HID + c];
            *(float4*)&sA[r * 136 + c] = v;
        }
        __syncthreads();

        float acc[4][8];
#pragma unroll
        for (int r = 0; r < 4; r++)
#pragma unroll
            for (int c = 0; c < 8; c++) acc[r][c] = 0.f;

        for (int k = 0; k < HID; k++) {
            float4 b0 = *(float4*)&sB[k * HID + c0];
            float4 b1 = *(float4*)&sB[k * HID + c0 + 4];
            float a[4];
#pragma unroll
            for (int r = 0; r < 4; r++) a[r] = sA[(rowg * 4 + r) * 136 + k];
#pragma unroll
            for (int r = 0; r < 4; r++) {
                acc[r][0] += a[r] * b0.x;
                acc[r][1] += a[r] * b0.y;
                acc[r][2] += a[r] * b0.z;
                acc[r][3] += a[r] * b0.w;
                acc[r][4] += a[r] * b1.x;
                acc[r][5] += a[r] * b1.y;
                acc[r][6] += a[r] * b1.z;
                acc[r][7] += a[r] * b1.w;
            }
        }

#pragma unroll
        for (int r = 0; r < 4; r++) {
            int row = rowBase + rowg * 4 + r;
            if (row < N) {
                float4 o0, o1;
                o0.x = acc[r][0] + bs[0]; o0.y = acc[r][1] + bs[1];
                o0.z = acc[r][2] + bs[2]; o0.w = acc[r][3] + bs[3];
                o1.x = acc[r][4] + bs[4]; o1.y = acc[r][5] + bs[5];
                o1.z = acc[r][6] + bs[6]; o1.w = acc[r][7] + bs[7];
                if (RELU) {
                    o0.x = fmaxf(o0.x, 0.f); o0.y = fmaxf(o0.y, 0.f);
                    o0.z = fmaxf(o0.z, 0.f); o0.w = fmaxf(o0.w, 0.f);
                    o1.x = fmaxf(o1.x, 0.f); o1.y = fmaxf(o1.y, 0.f);
                    o1.z = fmaxf(o1.z, 0.f); o1.w = fmaxf(o1.w, 0.f);
                }
                *(float4*)&out[(size_t)row * HID + c0] = o0;
                *(float4*)&out[(size_t)row * HID + c0 + 4] = o1;
            }
        }
    }
}

// ---------------- BN stats: per-column sum and sumsq ----------------
__global__ __launch_bounds__(256) void k_bnstats(const float* __restrict__ z,
                                                 float* __restrict__ stats) {
    __shared__ float sh[512];
    int t = threadIdx.x;
    int col = t & 127, half = t >> 7;
    int r0 = blockIdx.x * 512 + half;
    int rend = min(NN, blockIdx.x * 512 + 512);
    float s = 0.f, q = 0.f;
    for (int r = r0; r < rend; r += 2) {
        float v = z[(size_t)r * HID + col];
        s += v; q += v * v;
    }
    sh[t] = s;
    sh[256 + t] = q;
    __syncthreads();
    if (t < 128) {
        atomicAdd(&stats[t], sh[t] + sh[t + 128]);
        atomicAdd(&stats[128 + t], sh[256 + t] + sh[256 + t + 128]);
    }
}

// stats -> scale/shift in place
__global__ void k_bnfin(float* __restrict__ stats, const float* __restrict__ gamma,
                        const float* __restrict__ beta) {
    int c = threadIdx.x;
    float mean = stats[c] * (1.f / NN);
    float var = stats[128 + c] * (1.f / NN) - mean * mean;
    float sc = rsqrtf(var + BN_EPS) * gamma[c];
    stats[c] = sc;
    stats[128 + c] = beta[c] - mean * sc;
}

// h = relu(z*scale + shift)
__global__ __launch_bounds__(256) void k_bnapply(const float* __restrict__ z,
                                                 const float* __restrict__ stats,
                                                 float* __restrict__ h) {
    int idx = blockIdx.x * blockDim.x + threadIdx.x;
    if (idx >= NN * 32) return;
    int f4 = (idx & 31) << 2;
    size_t base = (size_t)(idx >> 5) * HID + f4;
    float4 v = *(const float4*)&z[base];
    float4 sc = *(const float4*)&stats[f4];
    float4 sf = *(const float4*)&stats[128 + f4];
    float4 o;
    o.x = fmaxf(v.x * sc.x + sf.x, 0.f);
    o.y = fmaxf(v.y * sc.y + sf.y, 0.f);
    o.z = fmaxf(v.z * sc.z + sf.z, 0.f);
    o.w = fmaxf(v.w * sc.w + sf.w, 0.f);
    *(float4*)&h[base] = o;
}

// ---------------- pooling: segment sums + counts ----------------
__global__ __launch_bounds__(256) void k_pool(const float* __restrict__ h,
                                              const int* __restrict__ batch,
                                              float* __restrict__ psums,
                                              float* __restrict__ pcnt) {
    int idx = blockIdx.x * blockDim.x + threadIdx.x;
    if (idx >= NN * 32) return;
    int n = idx >> 5;
    int f4 = (idx & 31) << 2;
    int g = batch[n];
    float4 v = *(const float4*)&h[(size_t)n * HID + f4];
    float* pp = &psums[(size_t)g * HID + f4];
    atomicAdd(pp + 0, v.x);
    atomicAdd(pp + 1, v.y);
    atomicAdd(pp + 2, v.z);
    atomicAdd(pp + 3, v.w);
    if (f4 == 0) atomicAdd(&pcnt[g], 1.f);
}

// ---------------- final: out[g] = concat(pooled, desc) @ Wf + bf -----------
__global__ __launch_bounds__(256) void k_final(const float* __restrict__ psums,
                                               const float* __restrict__ pcnt,
                                               const float* __restrict__ mol,
                                               const float* __restrict__ Wf,
                                               const float* __restrict__ bf,
                                               float* __restrict__ out) {
    int gid = (blockIdx.x * blockDim.x + threadIdx.x) >> 6;
    int lane = threadIdx.x & 63;
    if (gid >= NG) return;
    float inv = 1.f / fmaxf(pcnt[gid], 1.f);
    float acc = psums[(size_t)gid * HID + lane] * inv * Wf[lane] +
                psums[(size_t)gid * HID + 64 + lane] * inv * Wf[64 + lane];
    if (lane < DESCD) acc += mol[(size_t)gid * DESCD + lane] * Wf[HID + lane];
#pragma unroll
    for (int o = 32; o > 0; o >>= 1) acc += __shfl_down(acc, o);
    if (lane == 0) out[gid] = acc + bf[0];
}

extern "C" void kernel_launch(void* const* d_in, const int* in_sizes, int n_in,
                              void* d_out, int out_size, void* d_ws, size_t ws_size,
                              hipStream_t stream) {
    const float* x     = (const float*)d_in[0];
    const int*   ei    = (const int*)d_in[1];
    const float* ea    = (const float*)d_in[2];
    const int*   batch = (const int*)d_in[3];
    const float* mol   = (const float*)d_in[4];
    const float* Wp    = (const float*)d_in[5];
    const float* bp    = (const float*)d_in[6];
    const float* W1    = (const float*)d_in[7];
    const float* b1    = (const float*)d_in[8];
    const float* W2    = (const float*)d_in[9];
    const float* b2    = (const float*)d_in[10];
    const float* gamma = (const float*)d_in[11];
    const float* beta  = (const float*)d_in[12];
    const float* Wf    = (const float*)d_in[13];
    const float* bf    = (const float*)d_in[14];
    float* out = (float*)d_out;

    float* ws    = (float*)d_ws;
    float* h     = ws;
    float* bufA  = h + (size_t)NN * HID;
    float* bufB  = bufA + (size_t)NN * HID;
    float* stats = bufB + (size_t)NN * HID;
    float* psums = stats + 256;
    float* pcnt  = psums + (size_t)NG * HID;
    int*   deg    = (int*)(pcnt + NG);
    int*   rowptr = deg + NN;
    int*   cursor = rowptr + NN + 1;
    int*   eperm  = cursor + NN;
    int*   sperm  = eperm + NE;

    const int* src = ei;
    const int* dst = ei + NE;

    // CSR build (once per call; reused by all 3 layers)
    hipMemsetAsync(deg, 0, NN * sizeof(int), stream);
    k_hist<<<(NE + 255) / 256, 256, 0, stream>>>(dst, deg);
    k_scan<<<1, 1024, 0, stream>>>(deg, rowptr, cursor);
    k_fill<<<(NE + 255) / 256, 256, 0, stream>>>(src, dst, cursor, eperm, sperm);

    k_proj<<<(NN * HID) / 256, 256, 0, stream>>>(x, Wp, bp, h);

    for (int l = 0; l < NL; l++) {
        k_aggr<<<(NN * 64 + 255) / 256, 256, 0, stream>>>(h, ea, eperm, sperm, rowptr, bufA);
        k_gemm<true><<<(NN + 63) / 64, 256, 0, stream>>>(
            bufA, W1 + (size_t)l * HID * HID, b1 + l * HID, bufB, NN);
        k_gemm<false><<<(NN + 63) / 64, 256, 0, stream>>>(
            bufB, W2 + (size_t)l * HID * HID, b2 + l * HID, bufA, NN);
        hipMemsetAsync(stats, 0, 256 * sizeof(float), stream);
        k_bnstats<<<(NN + 511) / 512, 256, 0, stream>>>(bufA, stats);
        k_bnfin<<<1, 128, 0, stream>>>(stats, gamma + l * HID, beta + l * HID);
        k_bnapply<<<(NN * 32) / 256, 256, 0, stream>>>(bufA, stats, h);
    }

    hipMemsetAsync(psums, 0, (size_t)(NG * HID + NG) * sizeof(float), stream);
    k_pool<<<(NN * 32) / 256, 256, 0, stream>>>(h, batch, psums, pcnt);
    k_final<<<(NG * 64 + 255) / 256, 256, 0, stream>>>(psums, pcnt, mol, Wf, bf, out);
}

// Round 4
// 769.038 us; speedup vs baseline: 4.9635x; 1.5751x over previous
//
#include <hip/hip_runtime.h>
#include <hip/hip_bf16.h>

#define NN 50000
#define NE 600000
#define NG 1000
#define IND 16
#define HID 128
#define DESCD 17
#define NL 3
#define BN_EPS 1e-5f

typedef short s16x8 __attribute__((ext_vector_type(8)));
typedef float f32x4 __attribute__((ext_vector_type(4)));
typedef __hip_bfloat16 bfp16;
typedef __hip_bfloat162 bfp162;

// ---------------- CSR build ----------------
__global__ __launch_bounds__(256) void k_hist(const int* __restrict__ dst,
                                              int* __restrict__ deg) {
    int e = blockIdx.x * blockDim.x + threadIdx.x;
    if (e >= NE) return;
    atomicAdd(&deg[dst[e]], 1);
}

__global__ __launch_bounds__(1024) void k_scan(const int* __restrict__ deg,
                                               int* __restrict__ rowptr,
                                               int* __restrict__ cursor) {
    __shared__ int ssum[1024];
    const int t = threadIdx.x;
    const int CH = (NN + 1023) / 1024;
    int beg = t * CH, end = min(beg + CH, NN);
    int s = 0;
    for (int i = beg; i < end; i++) s += deg[i];
    ssum[t] = s;
    __syncthreads();
    int val = s;
    for (int off = 1; off < 1024; off <<= 1) {
        int tmp = (t >= off) ? ssum[t - off] : 0;
        __syncthreads();
        if (t >= off) ssum[t] += tmp;
        __syncthreads();
    }
    int run = ssum[t] - val;
    for (int i = beg; i < end; i++) {
        rowptr[i] = run;
        cursor[i] = run;
        run += deg[i];
    }
    if (t == 1023) rowptr[NN] = run;
}

__global__ __launch_bounds__(256) void k_fill(const int* __restrict__ src,
                                              const int* __restrict__ dst,
                                              int* __restrict__ cursor,
                                              int* __restrict__ eperm,
                                              int* __restrict__ sperm) {
    int e = blockIdx.x * blockDim.x + threadIdx.x;
    if (e >= NE) return;
    int pos = atomicAdd(&cursor[dst[e]], 1);
    eperm[pos] = e;
    sperm[pos] = src[e];
}

// ---------------- weight prep: W[k][n] f32 -> Wt[n][k] bf16 (6 mats) -------
// Layout: Wt[0..2] = W1 layers 0..2 ; Wt[3..5] = W2 layers 0..2
__global__ __launch_bounds__(256) void k_wprep(const float* __restrict__ W1,
                                               const float* __restrict__ W2,
                                               bfp16* __restrict__ Wt) {
    int id = blockIdx.x * blockDim.x + threadIdx.x;
    if (id >= 6 * HID * HID) return;
    int m = id >> 14;
    int rem = id & 16383;
    int n = rem >> 7, k = rem & 127;
    const float* Wsrc = (m < 3) ? (W1 + (size_t)m * HID * HID)
                                : (W2 + (size_t)(m - 3) * HID * HID);
    Wt[id] = __float2bfloat16(Wsrc[k * HID + n]);
}

// ---------------- h = x @ Wp + bp (bf16 out) ----------------
__global__ __launch_bounds__(256) void k_proj(const float* __restrict__ x,
                                              const float* __restrict__ Wp,
                                              const float* __restrict__ bp,
                                              bfp16* __restrict__ h) {
    int idx = blockIdx.x * blockDim.x + threadIdx.x;
    if (idx >= NN * HID) return;
    int row = idx >> 7, col = idx & 127;
    const float* xr = x + (size_t)row * IND;
    float acc = bp[col];
#pragma unroll
    for (int k = 0; k < IND; k++) acc += xr[k] * Wp[k * HID + col];
    h[idx] = __float2bfloat16(acc);
}

// ---------------- gather aggregation ----------------
// z[n] = h[n] + sum_e relu(h[src]+ea[e]); one wave per node, 2 feats/lane.
// MODE 0: read ea f32 via eperm.  MODE 1: same + write eab bf16 in CSR order.
// MODE 2: read eab bf16 linearly (no eperm).
template <int MODE>
__global__ __launch_bounds__(256) void k_aggr(const bfp16* __restrict__ h,
                                              const float* __restrict__ ea,
                                              bfp162* __restrict__ eab2,
                                              const int* __restrict__ eperm,
                                              const int* __restrict__ sperm,
                                              const int* __restrict__ rowptr,
                                              bfp16* __restrict__ z) {
    int n = (blockIdx.x * blockDim.x + threadIdx.x) >> 6;
    int lane = threadIdx.x & 63;
    if (n >= NN) return;
    const int f = lane * 2;
    int beg = rowptr[n], end = rowptr[n + 1];
    float ax = 0.f, ay = 0.f;
    int i = beg;
    for (; i + 1 < end; i += 2) {
        float2 a0, a1;
        int s0 = sperm[i], s1 = sperm[i + 1];
        if (MODE == 2) {
            a0 = __bfloat1622float2(eab2[(size_t)i * 64 + lane]);
            a1 = __bfloat1622float2(eab2[(size_t)(i + 1) * 64 + lane]);
        } else {
            int e0 = eperm[i], e1 = eperm[i + 1];
            a0 = *(const float2*)&ea[(size_t)e0 * HID + f];
            a1 = *(const float2*)&ea[(size_t)e1 * HID + f];
            if (MODE == 1) {
                eab2[(size_t)i * 64 + lane] = __float22bfloat162_rn(a0);
                eab2[(size_t)(i + 1) * 64 + lane] = __float22bfloat162_rn(a1);
            }
        }
        float2 h0 = __bfloat1622float2(*(const bfp162*)&h[(size_t)s0 * HID + f]);
        float2 h1 = __bfloat1622float2(*(const bfp162*)&h[(size_t)s1 * HID + f]);
        ax += fmaxf(a0.x + h0.x, 0.f) + fmaxf(a1.x + h1.x, 0.f);
        ay += fmaxf(a0.y + h0.y, 0.f) + fmaxf(a1.y + h1.y, 0.f);
    }
    if (i < end) {
        float2 a0;
        int s0 = sperm[i];
        if (MODE == 2) {
            a0 = __bfloat1622float2(eab2[(size_t)i * 64 + lane]);
        } else {
            int e0 = eperm[i];
            a0 = *(const float2*)&ea[(size_t)e0 * HID + f];
            if (MODE == 1) eab2[(size_t)i * 64 + lane] = __float22bfloat162_rn(a0);
        }
        float2 h0 = __bfloat1622float2(*(const bfp162*)&h[(size_t)s0 * HID + f]);
        ax += fmaxf(a0.x + h0.x, 0.f);
        ay += fmaxf(a0.y + h0.y, 0.f);
    }
    float2 hn = __bfloat1622float2(*(const bfp162*)&h[(size_t)n * HID + f]);
    float2 o;
    o.x = ax + hn.x;
    o.y = ay + hn.y;
    *(bfp162*)&z[(size_t)n * HID + f] = __float22bfloat162_rn(o);
}

// ---------------- MFMA GEMM: out = A[N,128] @ B[128,128] + bias ------------
// A bf16 row-major; Bt bf16 [n][k]; out bf16. 256 thr = 4 waves, 64-row tile.
// LDS 16B slots XOR-swizzled by (row&7) -> 2-way (free) ds_read_b128.
template <bool RELU>
__global__ __launch_bounds__(256) void k_gemmb(const bfp16* __restrict__ A,
                                               const bfp16* __restrict__ Bt,
                                               const float* __restrict__ bias,
                                               bfp16* __restrict__ out, int N) {
    __shared__ __align__(16) short sA[64 * 128];    // 16 KB
    __shared__ __align__(16) short sB[128 * 128];   // 32 KB
    const int t = threadIdx.x;
    const int rowBase = blockIdx.x * 64;

    // stage B (transposed weights), swizzled
    const short* Bg = (const short*)Bt;
    for (int g = t; g < 2048; g += 256) {
        int nrow = g >> 4, s = g & 15;
        *(float4*)&sB[nrow * 128 + ((s ^ (nrow & 7)) << 3)] = *(const float4*)&Bg[g * 8];
    }
    // stage A tile, swizzled; zero-fill tail rows
    const short* Ag = (const short*)A;
    for (int g = t; g < 1024; g += 256) {
        int r = g >> 4, s = g & 15;
        float4 v;
        if (rowBase + r < N)
            v = *(const float4*)&Ag[(size_t)(rowBase + r) * 128 + s * 8];
        else
            v = make_float4(0.f, 0.f, 0.f, 0.f);
        *(float4*)&sA[r * 128 + ((s ^ (r & 7)) << 3)] = v;
    }
    __syncthreads();

    const int w = t >> 6, lane = t & 63;
    const int l15 = lane & 15, lhi = lane >> 4;
    const int arow = (w << 4) + l15;
    const int abase = arow * 128, asw = arow & 7;
    const int bsw = l15 & 7;

    float bs[8];
#pragma unroll
    for (int c = 0; c < 8; c++) bs[c] = bias[c * 16 + l15];

    f32x4 acc[8];
#pragma unroll
    for (int c = 0; c < 8; c++) acc[c] = (f32x4){0.f, 0.f, 0.f, 0.f};

#pragma unroll
    for (int kk = 0; kk < 4; kk++) {
        int kslot = kk * 4 + lhi;
        s16x8 af = *(const s16x8*)&sA[abase + ((kslot ^ asw) << 3)];
#pragma unroll
        for (int c = 0; c < 8; c++) {
            int nrow = c * 16 + l15;
            s16x8 bfr = *(const s16x8*)&sB[nrow * 128 + ((kslot ^ bsw) << 3)];
            acc[c] = __builtin_amdgcn_mfma_f32_16x16x32_bf16(af, bfr, acc[c], 0, 0, 0);
        }
    }

    const int rb = rowBase + (w << 4) + lhi * 4;
#pragma unroll
    for (int c = 0; c < 8; c++) {
#pragma unroll
        for (int r = 0; r < 4; r++) {
            int row = rb + r;
            if (row < N) {
                float v = acc[c][r] + bs[c];
                if (RELU) v = fmaxf(v, 0.f);
                out[(size_t)row * 128 + c * 16 + l15] = __float2bfloat16(v);
            }
        }
    }
}

// ---------------- BN stats (bf16 in, f32 atomics) ----------------
__global__ __launch_bounds__(256) void k_bnstats(const bfp16* __restrict__ z,
                                                 float* __restrict__ stats) {
    __shared__ float shs[512];
    __shared__ float shq[512];
    int t = threadIdx.x;
    int cp = t & 63, rg = t >> 6;          // colpair 0..63, rowgroup 0..3
    int r0 = blockIdx.x * 512 + rg;
    int rend = min(NN, blockIdx.x * 512 + 512);
    float s0 = 0.f, q0 = 0.f, s1 = 0.f, q1 = 0.f;
    for (int r = r0; r < rend; r += 4) {
        float2 v = __bfloat1622float2(*(const bfp162*)&z[(size_t)r * HID + cp * 2]);
        s0 += v.x; q0 += v.x * v.x;
        s1 += v.y; q1 += v.y * v.y;
    }
    shs[rg * 128 + cp * 2] = s0; shs[rg * 128 + cp * 2 + 1] = s1;
    shq[rg * 128 + cp * 2] = q0; shq[rg * 128 + cp * 2 + 1] = q1;
    __syncthreads();
    if (t < 128) {
        float ss = shs[t] + shs[128 + t] + shs[256 + t] + shs[384 + t];
        float qq = shq[t] + shq[128 + t] + shq[256 + t] + shq[384 + t];
        atomicAdd(&stats[t], ss);
        atomicAdd(&stats[128 + t], qq);
    }
}

__global__ void k_bnfin(float* __restrict__ stats, const float* __restrict__ gamma,
                        const float* __restrict__ beta) {
    int c = threadIdx.x;
    float mean = stats[c] * (1.f / NN);
    float var = stats[128 + c] * (1.f / NN) - mean * mean;
    float sc = rsqrtf(var + BN_EPS) * gamma[c];
    stats[c] = sc;
    stats[128 + c] = beta[c] - mean * sc;
}

// h = relu(z*scale + shift), bf16 in/out
__global__ __launch_bounds__(256) void k_bnapply(const bfp16* __restrict__ z,
                                                 const float* __restrict__ stats,
                                                 bfp16* __restrict__ h) {
    int idx = blockIdx.x * blockDim.x + threadIdx.x;
    if (idx >= NN * 32) return;
    int f4 = (idx & 31) << 2;
    size_t base = (size_t)(idx >> 5) * HID + f4;
    float2 a = __bfloat1622float2(*(const bfp162*)&z[base]);
    float2 b = __bfloat1622float2(*(const bfp162*)&z[base + 2]);
    float4 sc = *(const float4*)&stats[f4];
    float4 sf = *(const float4*)&stats[128 + f4];
    float2 o0, o1;
    o0.x = fmaxf(a.x * sc.x + sf.x, 0.f);
    o0.y = fmaxf(a.y * sc.y + sf.y, 0.f);
    o1.x = fmaxf(b.x * sc.z + sf.z, 0.f);
    o1.y = fmaxf(b.y * sc.w + sf.w, 0.f);
    *(bfp162*)&h[base] = __float22bfloat162_rn(o0);
    *(bfp162*)&h[base + 2] = __float22bfloat162_rn(o1);
}

// ---------------- pooling ----------------
__global__ __launch_bounds__(256) void k_pool(const bfp16* __restrict__ h,
                                              const int* __restrict__ batch,
                                              float* __restrict__ psums,
                                              float* __restrict__ pcnt) {
    int idx = blockIdx.x * blockDim.x + threadIdx.x;
    if (idx >= NN * 32) return;
    int n = idx >> 5;
    int f4 = (idx & 31) << 2;
    int g = batch[n];
    size_t base = (size_t)n * HID + f4;
    float2 a = __bfloat1622float2(*(const bfp162*)&h[base]);
    float2 b = __bfloat1622float2(*(const bfp162*)&h[base + 2]);
    float* pp = &psums[(size_t)g * HID + f4];
    atomicAdd(pp + 0, a.x);
    atomicAdd(pp + 1, a.y);
    atomicAdd(pp + 2, b.x);
    atomicAdd(pp + 3, b.y);
    if (f4 == 0) atomicAdd(&pcnt[g], 1.f);
}

// ---------------- final ----------------
__global__ __launch_bounds__(256) void k_final(const float* __restrict__ psums,
                                               const float* __restrict__ pcnt,
                                               const float* __restrict__ mol,
                                               const float* __restrict__ Wf,
                                               const float* __restrict__ bfp,
                                               float* __restrict__ out) {
    int gid = (blockIdx.x * blockDim.x + threadIdx.x) >> 6;
    int lane = threadIdx.x & 63;
    if (gid >= NG) return;
    float inv = 1.f / fmaxf(pcnt[gid], 1.f);
    float acc = psums[(size_t)gid * HID + lane] * inv * Wf[lane] +
                psums[(size_t)gid * HID + 64 + lane] * inv * Wf[64 + lane];
    if (lane < DESCD) acc += mol[(size_t)gid * DESCD + lane] * Wf[HID + lane];
#pragma unroll
    for (int o = 32; o > 0; o >>= 1) acc += __shfl_down(acc, o);
    if (lane == 0) out[gid] = acc + bfp[0];
}

extern "C" void kernel_launch(void* const* d_in, const int* in_sizes, int n_in,
                              void* d_out, int out_size, void* d_ws, size_t ws_size,
                              hipStream_t stream) {
    const float* x     = (const float*)d_in[0];
    const int*   ei    = (const int*)d_in[1];
    const float* ea    = (const float*)d_in[2];
    const int*   batch = (const int*)d_in[3];
    const float* mol   = (const float*)d_in[4];
    const float* Wp    = (const float*)d_in[5];
    const float* bp    = (const float*)d_in[6];
    const float* W1    = (const float*)d_in[7];
    const float* b1    = (const float*)d_in[8];
    const float* W2    = (const float*)d_in[9];
    const float* b2    = (const float*)d_in[10];
    const float* gamma = (const float*)d_in[11];
    const float* beta  = (const float*)d_in[12];
    const float* Wf    = (const float*)d_in[13];
    const float* bf_   = (const float*)d_in[14];
    float* out = (float*)d_out;

    char* p = (char*)d_ws;
    size_t off = 0;
    auto alloc = [&](size_t bytes) {
        char* q = p + off;
        off = (off + bytes + 255) & ~(size_t)255;
        return q;
    };
    bfp16* h    = (bfp16*)alloc((size_t)NN * HID * 2);
    bfp16* z    = (bfp16*)alloc((size_t)NN * HID * 2);
    bfp16* y1   = (bfp16*)alloc((size_t)NN * HID * 2);
    bfp16* z2   = (bfp16*)alloc((size_t)NN * HID * 2);
    bfp16* Wt   = (bfp16*)alloc((size_t)6 * HID * HID * 2);
    float* stats = (float*)alloc(256 * 4);
    float* psums = (float*)alloc((size_t)NG * HID * 4);
    float* pcnt  = (float*)alloc(NG * 4);
    int* deg    = (int*)alloc(NN * 4);
    int* rowptr = (int*)alloc((NN + 16) * 4);
    int* cursor = (int*)alloc(NN * 4);
    int* eperm  = (int*)alloc((size_t)NE * 4);
    int* sperm  = (int*)alloc((size_t)NE * 4);
    size_t eab_bytes = (size_t)NE * HID * 2;
    bool eab_ok = (off + eab_bytes) <= ws_size;
    bfp162* eab2 = (bfp162*)alloc(eab_bytes);

    const int* src = ei;
    const int* dst = ei + NE;

    k_wprep<<<(6 * HID * HID + 255) / 256, 256, 0, stream>>>(W1, W2, Wt);

    hipMemsetAsync(deg, 0, NN * sizeof(int), stream);
    k_hist<<<(NE + 255) / 256, 256, 0, stream>>>(dst, deg);
    k_scan<<<1, 1024, 0, stream>>>(deg, rowptr, cursor);
    k_fill<<<(NE + 255) / 256, 256, 0, stream>>>(src, dst, cursor, eperm, sperm);

    k_proj<<<(NN * HID) / 256, 256, 0, stream>>>(x, Wp, bp, h);

    const int aggrGrid = (NN * 64) / 256;
    for (int l = 0; l < NL; l++) {
        if (l == 0) {
            if (eab_ok)
                k_aggr<1><<<aggrGrid, 256, 0, stream>>>(h, ea, eab2, eperm, sperm, rowptr, z);
            else
                k_aggr<0><<<aggrGrid, 256, 0, stream>>>(h, ea, eab2, eperm, sperm, rowptr, z);
        } else {
            if (eab_ok)
                k_aggr<2><<<aggrGrid, 256, 0, stream>>>(h, ea, eab2, eperm, sperm, rowptr, z);
            else
                k_aggr<0><<<aggrGrid, 256, 0, stream>>>(h, ea, eab2, eperm, sperm, rowptr, z);
        }
        // Wt layout: [W1_0, W1_1, W1_2, W2_0, W2_1, W2_2]
        k_gemmb<true><<<(NN + 63) / 64, 256, 0, stream>>>(
            z, Wt + (size_t)l * HID * HID, b1 + l * HID, y1, NN);
        k_gemmb<false><<<(NN + 63) / 64, 256, 0, stream>>>(
            y1, Wt + (size_t)(3 + l) * HID * HID, b2 + l * HID, z2, NN);
        hipMemsetAsync(stats, 0, 256 * sizeof(float), stream);
        k_bnstats<<<(NN + 511) / 512, 256, 0, stream>>>(z2, stats);
        k_bnfin<<<1, 128, 0, stream>>>(stats, gamma + l * HID, beta + l * HID);
        k_bnapply<<<(NN * 32) / 256, 256, 0, stream>>>(z2, stats, h);
    }

    hipMemsetAsync(psums, 0, (size_t)(NG * HID + NG) * sizeof(float), stream);
    k_pool<<<(NN * 32) / 256, 256, 0, stream>>>(h, batch, psums, pcnt);
    k_final<<<(NG * 64 + 255) / 256, 256, 0, stream>>>(psums, pcnt, mol, Wf, bf_, out);
}

// Round 5
// 642.520 us; speedup vs baseline: 5.9408x; 1.1969x over previous
//
#include <hip/hip_runtime.h>
#include <hip/hip_bf16.h>

#define NN 50000
#define NE 600000
#define NG 1000
#define IND 16
#define HID 128
#define DESCD 17
#define NL 3
#define BN_EPS 1e-5f

typedef short s16x8 __attribute__((ext_vector_type(8)));
typedef float f32x4 __attribute__((ext_vector_type(4)));
typedef __hip_bfloat16 bfp16;
typedef __hip_bfloat162 bfp162;

// ---------------- CSR build ----------------
__global__ __launch_bounds__(256) void k_hist(const int* __restrict__ dst,
                                              int* __restrict__ deg) {
    int e = blockIdx.x * blockDim.x + threadIdx.x;
    if (e >= NE) return;
    atomicAdd(&deg[dst[e]], 1);
}

__global__ __launch_bounds__(1024) void k_scan(const int* __restrict__ deg,
                                               int* __restrict__ rowptr,
                                               int* __restrict__ cursor) {
    __shared__ int ssum[1024];
    const int t = threadIdx.x;
    const int CH = (NN + 1023) / 1024;
    int beg = t * CH, end = min(beg + CH, NN);
    int s = 0;
    for (int i = beg; i < end; i++) s += deg[i];
    ssum[t] = s;
    __syncthreads();
    int val = s;
    for (int off = 1; off < 1024; off <<= 1) {
        int tmp = (t >= off) ? ssum[t - off] : 0;
        __syncthreads();
        if (t >= off) ssum[t] += tmp;
        __syncthreads();
    }
    int run = ssum[t] - val;
    for (int i = beg; i < end; i++) {
        rowptr[i] = run;
        cursor[i] = run;
        run += deg[i];
    }
    if (t == 1023) rowptr[NN] = run;
}

__global__ __launch_bounds__(256) void k_fill(const int* __restrict__ src,
                                              const int* __restrict__ dst,
                                              int* __restrict__ cursor,
                                              int2* __restrict__ perm) {
    int e = blockIdx.x * blockDim.x + threadIdx.x;
    if (e >= NE) return;
    int pos = atomicAdd(&cursor[dst[e]], 1);
    perm[pos] = make_int2(e, src[e]);
}

// ---------------- weight prep: W[k][n] f32 -> Wt[n][k] bf16 (6 mats) -------
// Layout: Wt[0..2] = W1 layers 0..2 ; Wt[3..5] = W2 layers 0..2
__global__ __launch_bounds__(256) void k_wprep(const float* __restrict__ W1,
                                               const float* __restrict__ W2,
                                               bfp16* __restrict__ Wt) {
    int id = blockIdx.x * blockDim.x + threadIdx.x;
    if (id >= 6 * HID * HID) return;
    int m = id >> 14;
    int rem = id & 16383;
    int n = rem >> 7, k = rem & 127;
    const float* Wsrc = (m < 3) ? (W1 + (size_t)m * HID * HID)
                                : (W2 + (size_t)(m - 3) * HID * HID);
    Wt[id] = __float2bfloat16(Wsrc[k * HID + n]);
}

// ---------------- h = x @ Wp + bp (bf16 out) ----------------
__global__ __launch_bounds__(256) void k_proj(const float* __restrict__ x,
                                              const float* __restrict__ Wp,
                                              const float* __restrict__ bp,
                                              bfp16* __restrict__ h) {
    int idx = blockIdx.x * blockDim.x + threadIdx.x;
    if (idx >= NN * HID) return;
    int row = idx >> 7, col = idx & 127;
    const float* xr = x + (size_t)row * IND;
    float acc = bp[col];
#pragma unroll
    for (int k = 0; k < IND; k++) acc += xr[k] * Wp[k * HID + col];
    h[idx] = __float2bfloat16(acc);
}

// ---------------- gather aggregation ----------------
// z[n] = h[n] + sum_e relu(h[src]+ea[e]); one wave per node, 2 feats/lane.
// MODE 1: read ea f32 via perm.x + write eab bf16 in CSR order.
// MODE 2: read eab bf16 linearly.
template <int MODE>
__global__ __launch_bounds__(256) void k_aggr(const bfp16* __restrict__ h,
                                              const float* __restrict__ ea,
                                              bfp162* __restrict__ eab2,
                                              const int2* __restrict__ perm,
                                              const int* __restrict__ rowptr,
                                              bfp16* __restrict__ z) {
    int nid = (blockIdx.x * blockDim.x + threadIdx.x) >> 6;
    int lane = threadIdx.x & 63;
    if (nid >= NN) return;
    const int f = lane * 2;
    int beg = rowptr[nid], end = rowptr[nid + 1];
    float ax = 0.f, ay = 0.f;
    int i = beg;
    for (; i + 3 < end; i += 4) {
#pragma unroll
        for (int u = 0; u < 4; u++) {
            int2 pr = perm[i + u];
            float2 a;
            if (MODE == 2) {
                a = __bfloat1622float2(eab2[(size_t)(i + u) * 64 + lane]);
            } else {
                a = *(const float2*)&ea[(size_t)pr.x * HID + f];
                eab2[(size_t)(i + u) * 64 + lane] = __float22bfloat162_rn(a);
            }
            float2 hv = __bfloat1622float2(*(const bfp162*)&h[(size_t)pr.y * HID + f]);
            ax += fmaxf(a.x + hv.x, 0.f);
            ay += fmaxf(a.y + hv.y, 0.f);
        }
    }
    for (; i < end; i++) {
        int2 pr = perm[i];
        float2 a;
        if (MODE == 2) {
            a = __bfloat1622float2(eab2[(size_t)i * 64 + lane]);
        } else {
            a = *(const float2*)&ea[(size_t)pr.x * HID + f];
            eab2[(size_t)i * 64 + lane] = __float22bfloat162_rn(a);
        }
        float2 hv = __bfloat1622float2(*(const bfp162*)&h[(size_t)pr.y * HID + f]);
        ax += fmaxf(a.x + hv.x, 0.f);
        ay += fmaxf(a.y + hv.y, 0.f);
    }
    float2 hn = __bfloat1622float2(*(const bfp162*)&h[(size_t)nid * HID + f]);
    *(bfp162*)&z[(size_t)nid * HID + f] =
        __float22bfloat162_rn(make_float2(ax + hn.x, ay + hn.y));
}

// ---------------- fused MLP: z2 = relu(A@W1+b1)@W2+b2, + BN col sums -------
// 256 thr = 4 waves, 64-row tile. LDS 16B slots XOR-swizzled by (row&7).
__global__ __launch_bounds__(256) void k_mlp(const bfp16* __restrict__ A,
                                             const bfp16* __restrict__ Wt1,
                                             const bfp16* __restrict__ Wt2,
                                             const float* __restrict__ b1,
                                             const float* __restrict__ b2,
                                             bfp16* __restrict__ z2,
                                             float* __restrict__ stats,
                                             int N) {
    __shared__ __align__(16) short sW1[128 * 128];  // 32 KB
    __shared__ __align__(16) short sW2[128 * 128];  // 32 KB
    __shared__ __align__(16) short sA[64 * 128];    // 16 KB (reused for y1, stats)
    const int t = threadIdx.x;
    const int rowBase = blockIdx.x * 64;

    const short* W1g = (const short*)Wt1;
    const short* W2g = (const short*)Wt2;
    for (int g = t; g < 2048; g += 256) {
        int nrow = g >> 4, s = g & 15;
        int sw = nrow * 128 + ((s ^ (nrow & 7)) << 3);
        *(float4*)&sW1[sw] = *(const float4*)&W1g[g * 8];
        *(float4*)&sW2[sw] = *(const float4*)&W2g[g * 8];
    }
    const short* Ag = (const short*)A;
    for (int g = t; g < 1024; g += 256) {
        int r = g >> 4, s = g & 15;
        float4 v = make_float4(0.f, 0.f, 0.f, 0.f);
        if (rowBase + r < N) v = *(const float4*)&Ag[(size_t)(rowBase + r) * 128 + s * 8];
        *(float4*)&sA[r * 128 + ((s ^ (r & 7)) << 3)] = v;
    }
    __syncthreads();

    const int w = t >> 6, lane = t & 63;
    const int l15 = lane & 15, lhi = lane >> 4;
    const int arow = (w << 4) + l15;
    const int abase = arow * 128, asw = arow & 7;
    const int bsw = l15 & 7;

    // phase 1: y1 = A @ W1
    f32x4 acc[8];
#pragma unroll
    for (int c = 0; c < 8; c++) acc[c] = (f32x4){0.f, 0.f, 0.f, 0.f};
#pragma unroll
    for (int kk = 0; kk < 4; kk++) {
        int kslot = kk * 4 + lhi;
        s16x8 af = *(const s16x8*)&sA[abase + ((kslot ^ asw) << 3)];
#pragma unroll
        for (int c = 0; c < 8; c++) {
            s16x8 bfr = *(const s16x8*)&sW1[(c * 16 + l15) * 128 + ((kslot ^ bsw) << 3)];
            acc[c] = __builtin_amdgcn_mfma_f32_16x16x32_bf16(af, bfr, acc[c], 0, 0, 0);
        }
    }
    __syncthreads();  // all sA reads done; reuse as y1 buffer

    {
        const int rowb = (w << 4);
#pragma unroll
        for (int c = 0; c < 8; c++) {
            float bb = b1[c * 16 + l15];
            int col = c * 16 + l15;
#pragma unroll
            for (int r = 0; r < 4; r++) {
                int row = rowb + lhi * 4 + r;
                float v = fmaxf(acc[c][r] + bb, 0.f);
                bfp16 bv = __float2bfloat16(v);
                sA[row * 128 + ((((col >> 3)) ^ (row & 7)) << 3) + (col & 7)] =
                    *reinterpret_cast<short*>(&bv);
            }
        }
    }
    __syncthreads();

    // phase 2: z2 = y1 @ W2
    f32x4 acc2[8];
#pragma unroll
    for (int c = 0; c < 8; c++) acc2[c] = (f32x4){0.f, 0.f, 0.f, 0.f};
#pragma unroll
    for (int kk = 0; kk < 4; kk++) {
        int kslot = kk * 4 + lhi;
        s16x8 af = *(const s16x8*)&sA[abase + ((kslot ^ asw) << 3)];
#pragma unroll
        for (int c = 0; c < 8; c++) {
            s16x8 bfr = *(const s16x8*)&sW2[(c * 16 + l15) * 128 + ((kslot ^ bsw) << 3)];
            acc2[c] = __builtin_amdgcn_mfma_f32_16x16x32_bf16(af, bfr, acc2[c], 0, 0, 0);
        }
    }

    // epilogue: store z2 + per-column sum/sumsq
    const int rb = rowBase + (w << 4) + lhi * 4;
    float scol[8], qcol[8];
#pragma unroll
    for (int c = 0; c < 8; c++) {
        float bb = b2[c * 16 + l15];
        float s = 0.f, q = 0.f;
#pragma unroll
        for (int r = 0; r < 4; r++) {
            int row = rb + r;
            float v = acc2[c][r] + bb;
            if (row < N) {
                z2[(size_t)row * 128 + c * 16 + l15] = __float2bfloat16(v);
                s += v;
                q += v * v;
            }
        }
        scol[c] = s;
        qcol[c] = q;
    }
#pragma unroll
    for (int c = 0; c < 8; c++) {
        scol[c] += __shfl_xor(scol[c], 16);
        scol[c] += __shfl_xor(scol[c], 32);
        qcol[c] += __shfl_xor(qcol[c], 16);
        qcol[c] += __shfl_xor(qcol[c], 32);
    }
    __syncthreads();  // done reading sA(y1); reuse as stats buffer
    float* sStat = (float*)sA;
    if (lane < 16) {
#pragma unroll
        for (int c = 0; c < 8; c++) {
            sStat[w * 256 + c * 16 + lane] = scol[c];
            sStat[w * 256 + 128 + c * 16 + lane] = qcol[c];
        }
    }
    __syncthreads();
    if (t < 128) {
        float ss = sStat[t] + sStat[256 + t] + sStat[512 + t] + sStat[768 + t];
        float qq = sStat[128 + t] + sStat[384 + t] + sStat[640 + t] + sStat[896 + t];
        atomicAdd(&stats[t], ss);
        atomicAdd(&stats[128 + t], qq);
    }
}

// ---------------- BN apply (+ optional fused pool) ----------------
template <bool POOL>
__global__ __launch_bounds__(256) void k_bnapply(const bfp16* __restrict__ z,
                                                 const float* __restrict__ stats,
                                                 const float* __restrict__ gamma,
                                                 const float* __restrict__ beta,
                                                 bfp16* __restrict__ h,
                                                 const int* __restrict__ batch,
                                                 float* __restrict__ psums) {
    int idx = blockIdx.x * blockDim.x + threadIdx.x;
    if (idx >= NN * 32) return;
    int f4 = (idx & 31) << 2;
    int n = idx >> 5;
    size_t base = (size_t)n * HID + f4;
    const float invn = 1.f / NN;
    float sc[4], sf[4];
#pragma unroll
    for (int j = 0; j < 4; j++) {
        int c = f4 + j;
        float mean = stats[c] * invn;
        float var = stats[128 + c] * invn - mean * mean;
        float s = rsqrtf(var + BN_EPS) * gamma[c];
        sc[j] = s;
        sf[j] = beta[c] - mean * s;
    }
    float2 a = __bfloat1622float2(*(const bfp162*)&z[base]);
    float2 b = __bfloat1622float2(*(const bfp162*)&z[base + 2]);
    float o0 = fmaxf(a.x * sc[0] + sf[0], 0.f);
    float o1 = fmaxf(a.y * sc[1] + sf[1], 0.f);
    float o2 = fmaxf(b.x * sc[2] + sf[2], 0.f);
    float o3 = fmaxf(b.y * sc[3] + sf[3], 0.f);
    bfp162 p0 = __float22bfloat162_rn(make_float2(o0, o1));
    bfp162 p1 = __float22bfloat162_rn(make_float2(o2, o3));
    *(bfp162*)&h[base] = p0;
    *(bfp162*)&h[base + 2] = p1;
    if (POOL) {
        int g = batch[n];
        float* pp = &psums[(size_t)g * HID + f4];
        atomicAdd(pp + 0, __bfloat162float(p0.x));
        atomicAdd(pp + 1, __bfloat162float(p0.y));
        atomicAdd(pp + 2, __bfloat162float(p1.x));
        atomicAdd(pp + 3, __bfloat162float(p1.y));
    }
}

// ---------------- final: out[g] = concat(pooled, desc) @ Wf + bf -----------
__global__ __launch_bounds__(256) void k_final(const float* __restrict__ psums,
                                               const int* __restrict__ batch,
                                               const float* __restrict__ mol,
                                               const float* __restrict__ Wf,
                                               const float* __restrict__ bfp,
                                               float* __restrict__ out) {
    int gid = (blockIdx.x * blockDim.x + threadIdx.x) >> 6;
    int lane = threadIdx.x & 63;
    if (gid >= NG) return;
    // binary search sorted batch for [lb, ub) of gid
    int lo = 0, hi = NN;
    while (lo < hi) { int m = (lo + hi) >> 1; if (batch[m] < gid) lo = m + 1; else hi = m; }
    int lb = lo;
    hi = NN;
    while (lo < hi) { int m = (lo + hi) >> 1; if (batch[m] <= gid) lo = m + 1; else hi = m; }
    int cnt = lo - lb;
    float inv = 1.f / fmaxf((float)cnt, 1.f);
    float acc = psums[(size_t)gid * HID + lane] * inv * Wf[lane] +
                psums[(size_t)gid * HID + 64 + lane] * inv * Wf[64 + lane];
    if (lane < DESCD) acc += mol[(size_t)gid * DESCD + lane] * Wf[HID + lane];
#pragma unroll
    for (int o = 32; o > 0; o >>= 1) acc += __shfl_down(acc, o);
    if (lane == 0) out[gid] = acc + bfp[0];
}

extern "C" void kernel_launch(void* const* d_in, const int* in_sizes, int n_in,
                              void* d_out, int out_size, void* d_ws, size_t ws_size,
                              hipStream_t stream) {
    const float* x     = (const float*)d_in[0];
    const int*   ei    = (const int*)d_in[1];
    const float* ea    = (const float*)d_in[2];
    const int*   batch = (const int*)d_in[3];
    const float* mol   = (const float*)d_in[4];
    const float* Wp    = (const float*)d_in[5];
    const float* bp    = (const float*)d_in[6];
    const float* W1    = (const float*)d_in[7];
    const float* b1    = (const float*)d_in[8];
    const float* W2    = (const float*)d_in[9];
    const float* b2    = (const float*)d_in[10];
    const float* gamma = (const float*)d_in[11];
    const float* beta  = (const float*)d_in[12];
    const float* Wf    = (const float*)d_in[13];
    const float* bf_   = (const float*)d_in[14];
    float* out = (float*)d_out;

    char* p = (char*)d_ws;
    size_t off = 0;
    auto alloc = [&](size_t bytes) {
        char* q = p + off;
        off = (off + bytes + 255) & ~(size_t)255;
        return q;
    };
    bfp16* h     = (bfp16*)alloc((size_t)NN * HID * 2);
    bfp16* z     = (bfp16*)alloc((size_t)NN * HID * 2);
    bfp16* z2    = (bfp16*)alloc((size_t)NN * HID * 2);
    bfp16* Wt    = (bfp16*)alloc((size_t)6 * HID * HID * 2);
    int2*  perm  = (int2*)alloc((size_t)NE * 8);
    int*   rowptr = (int*)alloc((NN + 16) * 4);
    int*   cursor = (int*)alloc(NN * 4);
    // contiguous zero-init region: deg | stats(3 layers) | psums
    size_t zoff = off;
    int*   deg    = (int*)alloc(NN * 4);
    float* stats3 = (float*)alloc(3 * 256 * 4);
    float* psums  = (float*)alloc((size_t)NG * HID * 4);
    size_t zlen = off - zoff;
    bfp162* eab2 = (bfp162*)alloc((size_t)NE * HID * 2);

    const int* src = ei;
    const int* dst = ei + NE;

    hipMemsetAsync(p + zoff, 0, zlen, stream);
    k_hist<<<(NE + 255) / 256, 256, 0, stream>>>(dst, deg);
    k_scan<<<1, 1024, 0, stream>>>(deg, rowptr, cursor);
    k_fill<<<(NE + 255) / 256, 256, 0, stream>>>(src, dst, cursor, perm);
    k_wprep<<<(6 * HID * HID + 255) / 256, 256, 0, stream>>>(W1, W2, Wt);
    k_proj<<<(NN * HID) / 256, 256, 0, stream>>>(x, Wp, bp, h);

    const int aggrGrid = (NN * 64) / 256;
    const int mlpGrid = (NN + 63) / 64;
    const int bnGrid = (NN * 32) / 256;
    for (int l = 0; l < NL; l++) {
        if (l == 0)
            k_aggr<1><<<aggrGrid, 256, 0, stream>>>(h, ea, eab2, perm, rowptr, z);
        else
            k_aggr<2><<<aggrGrid, 256, 0, stream>>>(h, ea, eab2, perm, rowptr, z);
        k_mlp<<<mlpGrid, 256, 0, stream>>>(
            z, Wt + (size_t)l * HID * HID, Wt + (size_t)(3 + l) * HID * HID,
            b1 + l * HID, b2 + l * HID, z2, stats3 + l * 256, NN);
        if (l < NL - 1)
            k_bnapply<false><<<bnGrid, 256, 0, stream>>>(
                z2, stats3 + l * 256, gamma + l * HID, beta + l * HID, h, batch, psums);
        else
            k_bnapply<true><<<bnGrid, 256, 0, stream>>>(
                z2, stats3 + l * 256, gamma + l * HID, beta + l * HID, h, batch, psums);
    }

    k_final<<<(NG * 64 + 255) / 256, 256, 0, stream>>>(psums, batch, mol, Wf, bf_, out);
}

// Round 7
// 431.800 us; speedup vs baseline: 8.8399x; 1.4880x over previous
//
#include <hip/hip_runtime.h>
#include <hip/hip_bf16.h>

#define NN 50000
#define NE 600000
#define NG 1000
#define IND 16
#define HID 128
#define DESCD 17
#define NL 3
#define BN_EPS 1e-5f
#define NB_SCAN 196  // ceil(NN/256)

typedef short s16x8 __attribute__((ext_vector_type(8)));
typedef float f32x4 __attribute__((ext_vector_type(4)));
typedef float f32x2 __attribute__((ext_vector_type(2)));
typedef __hip_bfloat16 bfp16;
typedef __hip_bfloat162 bfp162;

// ---------------- CSR build ----------------
__global__ __launch_bounds__(256) void k_hist(const int* __restrict__ dst,
                                              int* __restrict__ deg) {
    int e = blockIdx.x * blockDim.x + threadIdx.x;
    if (e >= NE) return;
    atomicAdd(&deg[dst[e]], 1);
}

// per-block sums of deg
__global__ __launch_bounds__(256) void k_part(const int* __restrict__ deg,
                                              int* __restrict__ partials) {
    __shared__ int sh[256];
    int i = blockIdx.x * 256 + threadIdx.x;
    sh[threadIdx.x] = (i < NN) ? deg[i] : 0;
    __syncthreads();
    for (int o = 128; o > 0; o >>= 1) {
        if (threadIdx.x < o) sh[threadIdx.x] += sh[threadIdx.x + o];
        __syncthreads();
    }
    if (threadIdx.x == 0) partials[blockIdx.x] = sh[0];
}

// exclusive scan of the 196 block partials (1 block)
__global__ __launch_bounds__(256) void k_scanpart(const int* __restrict__ partials,
                                                  int* __restrict__ poffs) {
    __shared__ int sh[256];
    int t = threadIdx.x;
    int v = (t < NB_SCAN) ? partials[t] : 0;
    sh[t] = v;
    __syncthreads();
    for (int o = 1; o < 256; o <<= 1) {
        int tmp = (t >= o) ? sh[t - o] : 0;
        __syncthreads();
        sh[t] += tmp;
        __syncthreads();
    }
    if (t < NB_SCAN) poffs[t] = sh[t] - v;
}

// per-element exclusive scan within block + block offset -> rowptr, cursor
__global__ __launch_bounds__(256) void k_scatter(const int* __restrict__ deg,
                                                 const int* __restrict__ poffs,
                                                 int* __restrict__ rowptr,
                                                 int* __restrict__ cursor) {
    __shared__ int sh[256];
    int b = blockIdx.x, t = threadIdx.x;
    int i = b * 256 + t;
    int v = (i < NN) ? deg[i] : 0;
    sh[t] = v;
    __syncthreads();
    for (int o = 1; o < 256; o <<= 1) {
        int tmp = (t >= o) ? sh[t - o] : 0;
        __syncthreads();
        sh[t] += tmp;
        __syncthreads();
    }
    int excl = sh[t] - v + poffs[b];
    if (i < NN) {
        rowptr[i] = excl;
        cursor[i] = excl;
        if (i == NN - 1) rowptr[NN] = excl + v;
    }
}

__global__ __launch_bounds__(256) void k_fill(const int* __restrict__ src,
                                              const int* __restrict__ dst,
                                              int* __restrict__ cursor,
                                              int2* __restrict__ perm) {
    int e = blockIdx.x * blockDim.x + threadIdx.x;
    if (e >= NE) return;
    int pos = atomicAdd(&cursor[dst[e]], 1);
    perm[pos] = make_int2(e, src[e]);
}

// ---------------- weight prep: W[k][n] f32 -> Wt[n][k] bf16 (6 mats) -------
// Layout: Wt[0..2] = W1 layers 0..2 ; Wt[3..5] = W2 layers 0..2
__global__ __launch_bounds__(256) void k_wprep(const float* __restrict__ W1,
                                               const float* __restrict__ W2,
                                               bfp16* __restrict__ Wt) {
    int id = blockIdx.x * blockDim.x + threadIdx.x;
    if (id >= 6 * HID * HID) return;
    int m = id >> 14;
    int rem = id & 16383;
    int n = rem >> 7, k = rem & 127;
    const float* Wsrc = (m < 3) ? (W1 + (size_t)m * HID * HID)
                                : (W2 + (size_t)(m - 3) * HID * HID);
    Wt[id] = __float2bfloat16(Wsrc[k * HID + n]);
}

// ---------------- h = x @ Wp + bp (bf16 out) ----------------
__global__ __launch_bounds__(256) void k_proj(const float* __restrict__ x,
                                              const float* __restrict__ Wp,
                                              const float* __restrict__ bp,
                                              bfp16* __restrict__ h) {
    int idx = blockIdx.x * blockDim.x + threadIdx.x;
    if (idx >= NN * HID) return;
    int row = idx >> 7, col = idx & 127;
    const float* xr = x + (size_t)row * IND;
    float acc = bp[col];
#pragma unroll
    for (int k = 0; k < IND; k++) acc += xr[k] * Wp[k * HID + col];
    h[idx] = __float2bfloat16(acc);
}

// ---------------- gather aggregation (+inline BN of previous layer) -------
// z[n] = H(n) + sum_e relu(H(src)+ea[e]),  H(v) = BN? relu(hz[v]*sc+sf) : hz[v]
// one wave per node, 2 feats/lane.
// MODE 1: read ea f32 via perm.x (nontemporal) + write eab bf16 CSR-ordered.
// MODE 2: read eab bf16 linearly.
template <int MODE, bool BN>
__global__ __launch_bounds__(256) void k_aggr(const bfp16* __restrict__ hz,
                                              const float* __restrict__ ea,
                                              bfp162* __restrict__ eab2,
                                              const int2* __restrict__ perm,
                                              const int* __restrict__ rowptr,
                                              const float* __restrict__ stats,
                                              const float* __restrict__ gamma,
                                              const float* __restrict__ beta,
                                              bfp16* __restrict__ z) {
    int nid = (blockIdx.x * blockDim.x + threadIdx.x) >> 6;
    int lane = threadIdx.x & 63;
    if (nid >= NN) return;
    const int f = lane * 2;

    float sc0 = 0.f, sf0 = 0.f, sc1 = 0.f, sf1 = 0.f;
    if (BN) {
        const float invn = 1.f / NN;
        float m0 = stats[f] * invn;
        float v0 = stats[128 + f] * invn - m0 * m0;
        sc0 = rsqrtf(v0 + BN_EPS) * gamma[f];
        sf0 = beta[f] - m0 * sc0;
        float m1 = stats[f + 1] * invn;
        float v1 = stats[128 + f + 1] * invn - m1 * m1;
        sc1 = rsqrtf(v1 + BN_EPS) * gamma[f + 1];
        sf1 = beta[f + 1] - m1 * sc1;
    }

    int beg = rowptr[nid], end = rowptr[nid + 1];
    float ax = 0.f, ay = 0.f;
    int i = beg;
    for (; i + 3 < end; i += 4) {
#pragma unroll
        for (int u = 0; u < 4; u++) {
            int2 pr = perm[i + u];
            float2 a;
            if (MODE == 2) {
                a = __bfloat1622float2(eab2[(size_t)(i + u) * 64 + lane]);
            } else {
                f32x2 av = __builtin_nontemporal_load(
                        (const f32x2*)&ea[(size_t)pr.x * HID + f]);
                a = make_float2(av.x, av.y);
                eab2[(size_t)(i + u) * 64 + lane] = __float22bfloat162_rn(a);
            }
            float2 hv = __bfloat1622float2(*(const bfp162*)&hz[(size_t)pr.y * HID + f]);
            if (BN) {
                hv.x = fmaxf(hv.x * sc0 + sf0, 0.f);
                hv.y = fmaxf(hv.y * sc1 + sf1, 0.f);
            }
            ax += fmaxf(a.x + hv.x, 0.f);
            ay += fmaxf(a.y + hv.y, 0.f);
        }
    }
    for (; i < end; i++) {
        int2 pr = perm[i];
        float2 a;
        if (MODE == 2) {
            a = __bfloat1622float2(eab2[(size_t)i * 64 + lane]);
        } else {
            f32x2 av = __builtin_nontemporal_load(
                    (const f32x2*)&ea[(size_t)pr.x * HID + f]);
            a = make_float2(av.x, av.y);
            eab2[(size_t)i * 64 + lane] = __float22bfloat162_rn(a);
        }
        float2 hv = __bfloat1622float2(*(const bfp162*)&hz[(size_t)pr.y * HID + f]);
        if (BN) {
            hv.x = fmaxf(hv.x * sc0 + sf0, 0.f);
            hv.y = fmaxf(hv.y * sc1 + sf1, 0.f);
        }
        ax += fmaxf(a.x + hv.x, 0.f);
        ay += fmaxf(a.y + hv.y, 0.f);
    }
    float2 hn = __bfloat1622float2(*(const bfp162*)&hz[(size_t)nid * HID + f]);
    if (BN) {
        hn.x = fmaxf(hn.x * sc0 + sf0, 0.f);
        hn.y = fmaxf(hn.y * sc1 + sf1, 0.f);
    }
    *(bfp162*)&z[(size_t)nid * HID + f] =
        __float22bfloat162_rn(make_float2(ax + hn.x, ay + hn.y));
}

// ---------------- fused MLP: z2 = relu(A@W1+b1)@W2+b2, + BN col sums -------
// 256 thr = 4 waves, 64-row tile. LDS 16B slots XOR-swizzled by (row&7).
__global__ __launch_bounds__(256) void k_mlp(const bfp16* __restrict__ A,
                                             const bfp16* __restrict__ Wt1,
                                             const bfp16* __restrict__ Wt2,
                                             const float* __restrict__ b1,
                                             const float* __restrict__ b2,
                                             bfp16* __restrict__ z2,
                                             float* __restrict__ stats,
                                             int N) {
    __shared__ __align__(16) short sW1[128 * 128];  // 32 KB
    __shared__ __align__(16) short sW2[128 * 128];  // 32 KB
    __shared__ __align__(16) short sA[64 * 128];    // 16 KB (reused for y1, stats)
    const int t = threadIdx.x;
    const int rowBase = blockIdx.x * 64;

    const short* W1g = (const short*)Wt1;
    const short* W2g = (const short*)Wt2;
    for (int g = t; g < 2048; g += 256) {
        int nrow = g >> 4, s = g & 15;
        int sw = nrow * 128 + ((s ^ (nrow & 7)) << 3);
        *(float4*)&sW1[sw] = *(const float4*)&W1g[g * 8];
        *(float4*)&sW2[sw] = *(const float4*)&W2g[g * 8];
    }
    const short* Ag = (const short*)A;
    for (int g = t; g < 1024; g += 256) {
        int r = g >> 4, s = g & 15;
        float4 v = make_float4(0.f, 0.f, 0.f, 0.f);
        if (rowBase + r < N) v = *(const float4*)&Ag[(size_t)(rowBase + r) * 128 + s * 8];
        *(float4*)&sA[r * 128 + ((s ^ (r & 7)) << 3)] = v;
    }
    __syncthreads();

    const int w = t >> 6, lane = t & 63;
    const int l15 = lane & 15, lhi = lane >> 4;
    const int arow = (w << 4) + l15;
    const int abase = arow * 128, asw = arow & 7;
    const int bsw = l15 & 7;

    // phase 1: y1 = A @ W1
    f32x4 acc[8];
#pragma unroll
    for (int c = 0; c < 8; c++) acc[c] = (f32x4){0.f, 0.f, 0.f, 0.f};
#pragma unroll
    for (int kk = 0; kk < 4; kk++) {
        int kslot = kk * 4 + lhi;
        s16x8 af = *(const s16x8*)&sA[abase + ((kslot ^ asw) << 3)];
#pragma unroll
        for (int c = 0; c < 8; c++) {
            s16x8 bfr = *(const s16x8*)&sW1[(c * 16 + l15) * 128 + ((kslot ^ bsw) << 3)];
            acc[c] = __builtin_amdgcn_mfma_f32_16x16x32_bf16(af, bfr, acc[c], 0, 0, 0);
        }
    }
    __syncthreads();  // all sA reads done; reuse as y1 buffer

    {
        const int rowb = (w << 4);
#pragma unroll
        for (int c = 0; c < 8; c++) {
            float bb = b1[c * 16 + l15];
            int col = c * 16 + l15;
#pragma unroll
            for (int r = 0; r < 4; r++) {
                int row = rowb + lhi * 4 + r;
                float v = fmaxf(acc[c][r] + bb, 0.f);
                bfp16 bv = __float2bfloat16(v);
                sA[row * 128 + ((((col >> 3)) ^ (row & 7)) << 3) + (col & 7)] =
                    *reinterpret_cast<short*>(&bv);
            }
        }
    }
    __syncthreads();

    // phase 2: z2 = y1 @ W2
    f32x4 acc2[8];
#pragma unroll
    for (int c = 0; c < 8; c++) acc2[c] = (f32x4){0.f, 0.f, 0.f, 0.f};
#pragma unroll
    for (int kk = 0; kk < 4; kk++) {
        int kslot = kk * 4 + lhi;
        s16x8 af = *(const s16x8*)&sA[abase + ((kslot ^ asw) << 3)];
#pragma unroll
        for (int c = 0; c < 8; c++) {
            s16x8 bfr = *(const s16x8*)&sW2[(c * 16 + l15) * 128 + ((kslot ^ bsw) << 3)];
            acc2[c] = __builtin_amdgcn_mfma_f32_16x16x32_bf16(af, bfr, acc2[c], 0, 0, 0);
        }
    }

    // epilogue: store z2 + per-column sum/sumsq
    const int rb = rowBase + (w << 4) + lhi * 4;
    float scol[8], qcol[8];
#pragma unroll
    for (int c = 0; c < 8; c++) {
        float bb = b2[c * 16 + l15];
        float s = 0.f, q = 0.f;
#pragma unroll
        for (int r = 0; r < 4; r++) {
            int row = rb + r;
            float v = acc2[c][r] + bb;
            if (row < N) {
                z2[(size_t)row * 128 + c * 16 + l15] = __float2bfloat16(v);
                s += v;
                q += v * v;
            }
        }
        scol[c] = s;
        qcol[c] = q;
    }
#pragma unroll
    for (int c = 0; c < 8; c++) {
        scol[c] += __shfl_xor(scol[c], 16);
        scol[c] += __shfl_xor(scol[c], 32);
        qcol[c] += __shfl_xor(qcol[c], 16);
        qcol[c] += __shfl_xor(qcol[c], 32);
    }
    __syncthreads();  // done reading sA(y1); reuse as stats buffer
    float* sStat = (float*)sA;
    if (lane < 16) {
#pragma unroll
        for (int c = 0; c < 8; c++) {
            sStat[w * 256 + c * 16 + lane] = scol[c];
            sStat[w * 256 + 128 + c * 16 + lane] = qcol[c];
        }
    }
    __syncthreads();
    if (t < 128) {
        float ss = sStat[t] + sStat[256 + t] + sStat[512 + t] + sStat[768 + t];
        float qq = sStat[128 + t] + sStat[384 + t] + sStat[640 + t] + sStat[896 + t];
        atomicAdd(&stats[t], ss);
        atomicAdd(&stats[128 + t], qq);
    }
}

// ---------------- final: BN(z2) -> per-graph mean pool -> dot with Wf ------
// one wave per graph (batch sorted); no atomics.
__global__ __launch_bounds__(256) void k_finalpool(const bfp16* __restrict__ z2,
                                                   const float* __restrict__ stats,
                                                   const float* __restrict__ gamma,
                                                   const float* __restrict__ beta,
                                                   const int* __restrict__ batch,
                                                   const float* __restrict__ mol,
                                                   const float* __restrict__ Wf,
                                                   const float* __restrict__ bfp,
                                                   float* __restrict__ out) {
    int gid = (blockIdx.x * blockDim.x + threadIdx.x) >> 6;
    int lane = threadIdx.x & 63;
    if (gid >= NG) return;
    const int f = lane * 2;

    const float invn = 1.f / NN;
    float m0 = stats[f] * invn;
    float v0 = stats[128 + f] * invn - m0 * m0;
    float sc0 = rsqrtf(v0 + BN_EPS) * gamma[f];
    float sf0 = beta[f] - m0 * sc0;
    float m1 = stats[f + 1] * invn;
    float v1 = stats[128 + f + 1] * invn - m1 * m1;
    float sc1 = rsqrtf(v1 + BN_EPS) * gamma[f + 1];
    float sf1 = beta[f + 1] - m1 * sc1;

    // range of this graph in sorted batch
    int lo = 0, hi = NN;
    while (lo < hi) { int m = (lo + hi) >> 1; if (batch[m] < gid) lo = m + 1; else hi = m; }
    int lb = lo;
    hi = NN;
    while (lo < hi) { int m = (lo + hi) >> 1; if (batch[m] <= gid) lo = m + 1; else hi = m; }
    int cnt = lo - lb;

    float sx = 0.f, sy = 0.f;
    for (int n = lb; n < lo; n++) {
        float2 v = __bfloat1622float2(*(const bfp162*)&z2[(size_t)n * HID + f]);
        sx += fmaxf(v.x * sc0 + sf0, 0.f);
        sy += fmaxf(v.y * sc1 + sf1, 0.f);
    }
    float inv = 1.f / fmaxf((float)cnt, 1.f);
    float acc = sx * inv * Wf[f] + sy * inv * Wf[f + 1];
    if (lane < DESCD) acc += mol[(size_t)gid * DESCD + lane] * Wf[HID + lane];
#pragma unroll
    for (int o = 32; o > 0; o >>= 1) acc += __shfl_down(acc, o);
    if (lane == 0) out[gid] = acc + bfp[0];
}

extern "C" void kernel_launch(void* const* d_in, const int* in_sizes, int n_in,
                              void* d_out, int out_size, void* d_ws, size_t ws_size,
                              hipStream_t stream) {
    const float* x     = (const float*)d_in[0];
    const int*   ei    = (const int*)d_in[1];
    const float* ea    = (const float*)d_in[2];
    const int*   batch = (const int*)d_in[3];
    const float* mol   = (const float*)d_in[4];
    const float* Wp    = (const float*)d_in[5];
    const float* bp    = (const float*)d_in[6];
    const float* W1    = (const float*)d_in[7];
    const float* b1    = (const float*)d_in[8];
    const float* W2    = (const float*)d_in[9];
    const float* b2    = (const float*)d_in[10];
    const float* gamma = (const float*)d_in[11];
    const float* beta  = (const float*)d_in[12];
    const float* Wf    = (const float*)d_in[13];
    const float* bf_   = (const float*)d_in[14];
    float* out = (float*)d_out;

    char* p = (char*)d_ws;
    size_t off = 0;
    auto alloc = [&](size_t bytes) {
        char* q = p + off;
        off = (off + bytes + 255) & ~(size_t)255;
        return q;
    };
    bfp16* h      = (bfp16*)alloc((size_t)NN * HID * 2);
    bfp16* z      = (bfp16*)alloc((size_t)NN * HID * 2);
    bfp16* z2     = (bfp16*)alloc((size_t)NN * HID * 2);
    bfp16* Wt     = (bfp16*)alloc((size_t)6 * HID * HID * 2);
    int2*  perm   = (int2*)alloc((size_t)NE * 8);
    int*   rowptr = (int*)alloc((NN + 16) * 4);
    int*   cursor = (int*)alloc(NN * 4);
    int*   partials = (int*)alloc(NB_SCAN * 4);
    int*   poffs    = (int*)alloc(NB_SCAN * 4);
    // contiguous zero-init region: deg | stats(3 layers)
    size_t zoff = off;
    int*   deg    = (int*)alloc(NN * 4);
    float* stats3 = (float*)alloc(3 * 256 * 4);
    size_t zlen = off - zoff;
    bfp162* eab2 = (bfp162*)alloc((size_t)NE * HID * 2);

    const int* src = ei;
    const int* dst = ei + NE;

    (void)hipMemsetAsync(p + zoff, 0, zlen, stream);
    k_hist<<<(NE + 255) / 256, 256, 0, stream>>>(dst, deg);
    k_part<<<NB_SCAN, 256, 0, stream>>>(deg, partials);
    k_scanpart<<<1, 256, 0, stream>>>(partials, poffs);
    k_scatter<<<NB_SCAN, 256, 0, stream>>>(deg, poffs, rowptr, cursor);
    k_fill<<<(NE + 255) / 256, 256, 0, stream>>>(src, dst, cursor, perm);
    k_wprep<<<(6 * HID * HID + 255) / 256, 256, 0, stream>>>(W1, W2, Wt);
    k_proj<<<(NN * HID) / 256, 256, 0, stream>>>(x, Wp, bp, h);

    const int aggrGrid = (NN * 64) / 256;
    const int mlpGrid = (NN + 63) / 64;
    for (int l = 0; l < NL; l++) {
        if (l == 0)
            k_aggr<1, false><<<aggrGrid, 256, 0, stream>>>(
                h, ea, eab2, perm, rowptr, nullptr, nullptr, nullptr, z);
        else
            k_aggr<2, true><<<aggrGrid, 256, 0, stream>>>(
                z2, nullptr, eab2, perm, rowptr, stats3 + (l - 1) * 256,
                gamma + (l - 1) * HID, beta + (l - 1) * HID, z);
        k_mlp<<<mlpGrid, 256, 0, stream>>>(
            z, Wt + (size_t)l * HID * HID, Wt + (size_t)(3 + l) * HID * HID,
            b1 + l * HID, b2 + l * HID, z2, stats3 + l * 256, NN);
    }

    k_finalpool<<<(NG * 64) / 256, 256, 0, stream>>>(
        z2, stats3 + 2 * 256, gamma + 2 * HID, beta + 2 * HID,
        batch, mol, Wf, bf_, out);
}